// Round 1
// baseline (75203.717 us; speedup 1.0000x reference)
//
#include <hip/hip_runtime.h>
#include <math.h>

// ---------------------------------------------------------------------------
// helpers
// ---------------------------------------------------------------------------
__device__ __forceinline__ float sigm(float x) { return 1.0f / (1.0f + __expf(-x)); }

__device__ __forceinline__ float waveSum(float v) {
#pragma unroll
  for (int off = 32; off > 0; off >>= 1) v += __shfl_xor(v, off);
  return v;
}

// ---------------------------------------------------------------------------
// char CNN + elmo concat  -> x_all (4224 x 356)
// block = 128 threads, grid = 4224 (one token per block)
// ---------------------------------------------------------------------------
__global__ __launch_bounds__(128) void cnn_embed_kernel(
    const int* __restrict__ chars_ctx, const int* __restrict__ chars_qry,
    const float* __restrict__ elmo_ctx, const float* __restrict__ elmo_qry,
    const float* __restrict__ char_emb, const float* __restrict__ conv_w,
    const float* __restrict__ conv_b, float* __restrict__ x_all)
{
  int n = blockIdx.x;
  const int*   chars = (n < 4096) ? (chars_ctx + n * 16) : (chars_qry + (n - 4096) * 16);
  const float* elmo  = (n < 4096) ? (elmo_ctx + (size_t)n * 256)
                                  : (elmo_qry + (size_t)(n - 4096) * 256);
  __shared__ float xl[1600];   // [emb_dim=100][pos=16]
  __shared__ int   cidx[16];
  int tid = threadIdx.x;
  if (tid < 16) cidx[tid] = chars[tid];
  __syncthreads();
  for (int e = tid; e < 1600; e += 128) {
    int i = e >> 4, p = e & 15;
    xl[e] = char_emb[cidx[p] * 100 + i];
  }
  __syncthreads();
  if (tid < 100) {
    int o = tid;
    float acc[16];
#pragma unroll
    for (int p = 0; p < 16; ++p) acc[p] = 0.f;
    const float* wo = conv_w + o * 500;
    for (int i = 0; i < 100; ++i) {
      const float* xi = xl + i * 16;
#pragma unroll
      for (int k = 0; k < 5; ++k) {
        float w = wo[i * 5 + k];
#pragma unroll
        for (int p = 0; p < 16; ++p) {
          int src = p + k - 2;
          if (src >= 0 && src < 16) acc[p] += w * xi[src];
        }
      }
    }
    float m = acc[0];
#pragma unroll
    for (int p = 1; p < 16; ++p) m = fmaxf(m, acc[p]);
    x_all[(size_t)n * 356 + o] = m + conv_b[o];
  }
  for (int j = tid; j < 256; j += 128)
    x_all[(size_t)n * 356 + 100 + j] = elmo[j];
}

// ---------------------------------------------------------------------------
// generic fp32 GEMM:  C[M,N] = A[M,K] @ B[N,K]^T + bias[N]
// 64x64 tile, BK=16, block=256, 4x4 per thread
// ---------------------------------------------------------------------------
#define BMT 64
#define BNT 64
#define BKT 16

__global__ __launch_bounds__(256) void gemm_abt(
    const float* __restrict__ A, const float* __restrict__ B,
    const float* __restrict__ bias, float* __restrict__ C,
    int M, int N, int K)
{
  __shared__ float As[BKT][BMT + 4];
  __shared__ float Bs[BKT][BNT + 4];
  int tid = threadIdx.x;
  int bm = blockIdx.y * BMT, bn = blockIdx.x * BNT;
  int tm = (tid >> 4) << 2;   // 0..60
  int tn = (tid & 15) << 2;   // 0..60
  float acc[4][4];
#pragma unroll
  for (int i = 0; i < 4; ++i)
#pragma unroll
    for (int j = 0; j < 4; ++j) acc[i][j] = 0.f;

  for (int k0 = 0; k0 < K; k0 += BKT) {
    for (int e = tid; e < BMT * BKT; e += 256) {
      int m = e >> 4, kk = e & 15;
      int gm = bm + m, gk = k0 + kk;
      As[kk][m] = (gm < M && gk < K) ? A[(size_t)gm * K + gk] : 0.f;
    }
    for (int e = tid; e < BNT * BKT; e += 256) {
      int nn = e >> 4, kk = e & 15;
      int gn = bn + nn, gk = k0 + kk;
      Bs[kk][nn] = (gn < N && gk < K) ? B[(size_t)gn * K + gk] : 0.f;
    }
    __syncthreads();
#pragma unroll
    for (int kk = 0; kk < BKT; ++kk) {
      float a[4], b[4];
#pragma unroll
      for (int i = 0; i < 4; ++i) a[i] = As[kk][tm + i];
#pragma unroll
      for (int j = 0; j < 4; ++j) b[j] = Bs[kk][tn + j];
#pragma unroll
      for (int i = 0; i < 4; ++i)
#pragma unroll
        for (int j = 0; j < 4; ++j) acc[i][j] += a[i] * b[j];
    }
    __syncthreads();
  }
#pragma unroll
  for (int i = 0; i < 4; ++i) {
    int gm = bm + tm + i;
    if (gm >= M) continue;
#pragma unroll
    for (int j = 0; j < 4; ++j) {
      int gn = bn + tn + j;
      if (gn < N) {
        float v = acc[i][j];
        if (bias) v += bias[gn];
        C[(size_t)gm * N + gn] = v;
      }
    }
  }
}

// ---------------------------------------------------------------------------
// highway combine: x = sig(g)*relu(p) + (1-sig(g))*x   (elementwise)
// ---------------------------------------------------------------------------
__global__ void highway_combine(float* __restrict__ x, const float* __restrict__ g,
                                const float* __restrict__ p, int total)
{
  int i = blockIdx.x * blockDim.x + threadIdx.x;
  if (i < total) {
    float gg = sigm(g[i]);
    float pp = fmaxf(p[i], 0.f);
    x[i] = gg * pp + (1.f - gg) * x[i];
  }
}

// ---------------------------------------------------------------------------
// persistent BiLSTM scan kernel.
// grid = 64 WGs (dir = blockIdx.x&1, wg = blockIdx.x>>1, 32 WGs/dir), block=512.
// Each WG owns 12 hidden units (48 Whh rows) kept entirely in VGPRs
// (6 rows/wave x 6 chunks of 64). h is exchanged each step through `out`
// with agent-scope atomics + a per-direction monotonic counter barrier.
// xw layout: [row][dir*1424 + gate*356 + j], ld = 2848 (bias pre-added).
// out layout: [row][dir*356 + j], ld = 712.
// ---------------------------------------------------------------------------
#define NWG 32

__global__ __launch_bounds__(512, 1) void lstm_scan_kernel(
    const float* __restrict__ xw, const float* __restrict__ whh,
    const float* __restrict__ h0, float* out,
    int row0, int N, unsigned* bar)
{
  const int tid  = threadIdx.x;
  const int dir  = blockIdx.x & 1;
  const int wg   = blockIdx.x >> 1;
  const int lane = tid & 63;
  const int wv   = tid >> 6;          // 0..7
  const int j0   = wg * 12;
  const float* whh_d = whh + (size_t)dir * 1424 * 356;
  const float* h0_d  = h0 + dir * 356;
  const int xcol0 = dir * 1424;
  const int ocol0 = dir * 356;
  unsigned* bar_d = bar + dir * 32;   // separate cacheline per direction

  __shared__ float h_lds[384];
  __shared__ float z_lds[48];
  __shared__ float c_lds[12];

  // --- load this WG's Whh slice into registers: rows rr = wv*6+q,
  //     gate = rr/12, jj = rr%12, global row = gate*356 + (j0+jj)
  float wreg[6][6];
#pragma unroll
  for (int q = 0; q < 6; ++q) {
    int rr = wv * 6 + q;
    int gate = rr / 12, jj = rr % 12;
    int j = j0 + jj;
    bool v = (j < 356);
    int row_g = gate * 356 + j;
#pragma unroll
    for (int ii = 0; ii < 6; ++ii) {
      int k = lane + ii * 64;
      wreg[q][ii] = (v && k < 356) ? whh_d[(size_t)row_g * 356 + k] : 0.f;
    }
  }
  // init h (pad zeroed), c (c0 == h0 vector in the reference)
  for (int k = tid; k < 384; k += 512) h_lds[k] = (k < 356) ? h0_d[k] : 0.f;
  if (tid < 12) { int j = j0 + tid; c_lds[tid] = (j < 356) ? h0_d[j] : 0.f; }
  __syncthreads();

  for (int t = 0; t < N; ++t) {
    int row = dir ? (N - 1 - t) : t;
    size_t grow = (size_t)(row0 + row);

    // z init from precomputed xW (+bias)
    if (tid < 48) {
      int gate = tid / 12, jj = tid % 12, j = j0 + jj;
      z_lds[tid] = (j < 356) ? xw[grow * 2848 + xcol0 + gate * 356 + j] : 0.f;
    }
    __syncthreads();   // z ready; previous h reload also ready

    // dot products: z[rr] += wreg_row . h
#pragma unroll
    for (int q = 0; q < 6; ++q) {
      float s = 0.f;
#pragma unroll
      for (int ii = 0; ii < 6; ++ii) s += wreg[q][ii] * h_lds[lane + ii * 64];
      s = waveSum(s);
      if (lane == 0) z_lds[wv * 6 + q] += s;
    }
    __syncthreads();

    // gate update + publish h
    if (tid < 12) {
      int j = j0 + tid;
      if (j < 356) {
        float zi = z_lds[tid], zf = z_lds[12 + tid];
        float zg = z_lds[24 + tid], zo = z_lds[36 + tid];
        float c = sigm(zf) * c_lds[tid] + sigm(zi) * tanhf(zg);
        float h = sigm(zo) * tanhf(c);
        c_lds[tid] = c;
        __hip_atomic_store(&out[grow * 712 + ocol0 + j], h,
                           __ATOMIC_RELAXED, __HIP_MEMORY_SCOPE_AGENT);
      }
    }
    __syncthreads();   // drains vmem (stores at coherent point) before arrive

    if (tid == 0) {
      __hip_atomic_fetch_add(bar_d, 1u, __ATOMIC_ACQ_REL, __HIP_MEMORY_SCOPE_AGENT);
      unsigned target = (unsigned)(t + 1) * NWG;
      while (__hip_atomic_load(bar_d, __ATOMIC_ACQUIRE, __HIP_MEMORY_SCOPE_AGENT) < target)
        __builtin_amdgcn_s_sleep(1);
    }
    __syncthreads();

    // reload full h for next step (row just produced by all WGs of this dir)
    for (int k = tid; k < 356; k += 512)
      h_lds[k] = __hip_atomic_load(&out[grow * 712 + ocol0 + k],
                                   __ATOMIC_RELAXED, __HIP_MEMORY_SCOPE_AGENT);
    // next iteration's first __syncthreads() covers this write
  }
}

// ---------------------------------------------------------------------------
// attention: s2[j] = Q[j] . w_q
// ---------------------------------------------------------------------------
__global__ __launch_bounds__(64) void qdot_kernel(
    const float* __restrict__ Q, const float* __restrict__ sim_w, float* __restrict__ s2)
{
  int j = blockIdx.x;
  int lane = threadIdx.x;
  const float* q  = Q + (size_t)j * 712;
  const float* wq = sim_w + 712;
  float s = 0.f;
  for (int k = lane; k < 712; k += 64) s += q[k] * wq[k];
  s = waveSum(s);
  if (lane == 0) s2[j] = s;
}

// ---------------------------------------------------------------------------
// per-context-row: sim row, row max (for q2c), row softmax, c2q,
// and qac columns [0,2136)
// ---------------------------------------------------------------------------
__global__ __launch_bounds__(256) void attn_row_kernel(
    const float* __restrict__ CQ, const float* __restrict__ sim_w,
    const float* __restrict__ s2, float* __restrict__ rowm, float* __restrict__ qac)
{
  int i = blockIdx.x;   // 0..4095
  int tid = threadIdx.x;
  const float* Q = CQ + (size_t)4096 * 712;
  __shared__ float crow[712], cw[712], prow[128], red[256];
  const float* ci = CQ + (size_t)i * 712;

  float s1p = 0.f;
  for (int k = tid; k < 712; k += 256) {
    float v = ci[k];
    crow[k] = v;
    cw[k] = v * sim_w[1424 + k];
    s1p += v * sim_w[k];
  }
  red[tid] = s1p;
  __syncthreads();
  for (int s = 128; s > 0; s >>= 1) { if (tid < s) red[tid] += red[tid + s]; __syncthreads(); }
  float s1 = red[0];

  int lane = tid & 63, wv = tid >> 6;   // 4 waves
  for (int j = wv; j < 128; j += 4) {
    const float* qj = Q + (size_t)j * 712;
    float s = 0.f;
    for (int k = lane; k < 712; k += 64) s += cw[k] * qj[k];
    s = waveSum(s);
    if (lane == 0) prow[j] = s1 + s2[j] + s;
  }
  __syncthreads();

  // softmax over 128 (also record row max)
  float v = (tid < 128) ? prow[tid] : -1e30f;
  red[tid] = v;
  __syncthreads();
  for (int s = 128; s > 0; s >>= 1) { if (tid < s) red[tid] = fmaxf(red[tid], red[tid + s]); __syncthreads(); }
  float m = red[0];
  __syncthreads();
  float e = (tid < 128) ? __expf(prow[tid] - m) : 0.f;
  red[tid] = e;
  __syncthreads();
  for (int s = 128; s > 0; s >>= 1) { if (tid < s) red[tid] += red[tid + s]; __syncthreads(); }
  float denom = red[0];
  if (tid < 128) prow[tid] = e / denom;
  if (tid == 0) rowm[i] = m;
  __syncthreads();

  // c2q row + qac columns
  size_t qb = (size_t)i * 2848;
  for (int k = tid; k < 712; k += 256) {
    float acc = 0.f;
    for (int j = 0; j < 128; ++j) acc += prow[j] * Q[(size_t)j * 712 + k];
    float cv = crow[k];
    qac[qb + k]        = cv;
    qac[qb + 712 + k]  = acc;
    qac[qb + 1424 + k] = cv * acc;
  }
}

// ---------------------------------------------------------------------------
// softmax over a length-4096 vector (single block)
// ---------------------------------------------------------------------------
__global__ __launch_bounds__(256) void softmax_4096(const float* __restrict__ in,
                                                    float* __restrict__ out)
{
  __shared__ float red[256];
  int tid = threadIdx.x;
  float m = -1e30f;
  for (int i = tid; i < 4096; i += 256) m = fmaxf(m, in[i]);
  red[tid] = m;
  __syncthreads();
  for (int s = 128; s > 0; s >>= 1) { if (tid < s) red[tid] = fmaxf(red[tid], red[tid + s]); __syncthreads(); }
  m = red[0];
  __syncthreads();
  float sum = 0.f;
  for (int i = tid; i < 4096; i += 256) sum += __expf(in[i] - m);
  red[tid] = sum;
  __syncthreads();
  for (int s = 128; s > 0; s >>= 1) { if (tid < s) red[tid] += red[tid + s]; __syncthreads(); }
  float denom = red[0];
  for (int i = tid; i < 4096; i += 256) out[i] = __expf(in[i] - m) / denom;
}

// ---------------------------------------------------------------------------
// q2c[k] = sum_i a[i]*C[i,k]
// ---------------------------------------------------------------------------
__global__ __launch_bounds__(256) void q2c_kernel(
    const float* __restrict__ CQ, const float* __restrict__ rowa, float* __restrict__ q2c)
{
  int k = blockIdx.x * 256 + threadIdx.x;
  if (k < 712) {
    float acc = 0.f;
    for (int i = 0; i < 4096; ++i) acc += rowa[i] * CQ[(size_t)i * 712 + k];
    q2c[k] = acc;
  }
}

// qac columns [2136,2848) = C * q2c
__global__ __launch_bounds__(256) void qac_finish_kernel(
    const float* __restrict__ CQ, const float* __restrict__ q2c, float* __restrict__ qac)
{
  int i = blockIdx.x;
  int tid = threadIdx.x;
  for (int k = tid; k < 712; k += 256)
    qac[(size_t)i * 2848 + 2136 + k] = CQ[(size_t)i * 712 + k] * q2c[k];
}

// logits[i] = qac[i,:].w[0:2848] + Mx[i,:].w[2848:3560]
__global__ __launch_bounds__(256) void logits_kernel(
    const float* __restrict__ qac, const float* __restrict__ Mx,
    const float* __restrict__ w, float* __restrict__ logits)
{
  int i = blockIdx.x, tid = threadIdx.x;
  __shared__ float red[256];
  float s = 0.f;
  const float* qr = qac + (size_t)i * 2848;
  for (int k = tid; k < 2848; k += 256) s += qr[k] * w[k];
  const float* mr = Mx + (size_t)i * 712;
  for (int k = tid; k < 712; k += 256) s += mr[k] * w[2848 + k];
  red[tid] = s;
  __syncthreads();
  for (int st = 128; st > 0; st >>= 1) { if (tid < st) red[tid] += red[tid + st]; __syncthreads(); }
  if (tid == 0) logits[i] = red[0];
}

// ---------------------------------------------------------------------------
// host side
// ---------------------------------------------------------------------------
extern "C" void kernel_launch(void* const* d_in, const int* in_sizes, int n_in,
                              void* d_out, int out_size, void* d_ws, size_t ws_size,
                              hipStream_t stream)
{
  const int*   chars_ctx = (const int*)d_in[0];
  const int*   chars_qry = (const int*)d_in[1];
  const float* elmo_ctx  = (const float*)d_in[2];
  const float* elmo_qry  = (const float*)d_in[3];
  const float* char_emb  = (const float*)d_in[4];
  const float* conv_w    = (const float*)d_in[5];
  const float* conv_b    = (const float*)d_in[6];
  const float* hw_plain_w = (const float*)d_in[7];
  const float* hw_plain_b = (const float*)d_in[8];
  const float* hw_gate_w  = (const float*)d_in[9];
  const float* hw_gate_b  = (const float*)d_in[10];
  const float* ctx_Wih   = (const float*)d_in[11];
  const float* ctx_Whh   = (const float*)d_in[12];
  const float* ctx_b     = (const float*)d_in[13];
  const float* sim_w     = (const float*)d_in[14];
  const float* mod1_Wih  = (const float*)d_in[15];
  const float* mod1_Whh  = (const float*)d_in[16];
  const float* mod1_b    = (const float*)d_in[17];
  const float* mod2_Wih  = (const float*)d_in[18];
  const float* mod2_Whh  = (const float*)d_in[19];
  const float* mod2_b    = (const float*)d_in[20];
  const float* pos_Wih   = (const float*)d_in[21];
  const float* pos_Whh   = (const float*)d_in[22];
  const float* pos_b     = (const float*)d_in[23];
  const float* pos1_w    = (const float*)d_in[24];
  const float* pos2_w    = (const float*)d_in[25];
  const float* h0_ctx_c  = (const float*)d_in[26];
  const float* h0_ctx_q  = (const float*)d_in[27];
  const float* h0_mod    = (const float*)d_in[28];
  const float* h0_pos    = (const float*)d_in[29];
  float* outp = (float*)d_out;

  // workspace layout
  float* ws = (float*)d_ws;
  size_t off = 0;
  auto alloc = [&](size_t n) { float* p = ws + off; off += n; return p; };
  float* x_all  = alloc(4224ull * 356);
  float* gbuf   = alloc(4224ull * 356);
  float* pbuf   = alloc(4224ull * 356);
  float* xw_all = alloc(4224ull * 2848);
  float* CQ     = alloc(4224ull * 712);
  float* M1     = alloc(4096ull * 712);
  float* Mm     = alloc(4096ull * 712);
  float* M2     = alloc(4096ull * 712);
  float* qac    = alloc(4096ull * 2848);
  float* s2v    = alloc(128);
  float* rowm   = alloc(4096);
  float* rowa   = alloc(4096);
  float* q2cv   = alloc(1024);
  float* logits = alloc(8192);
  unsigned* bars = (unsigned*)(ws + off);
  off += 512;

  auto cdiv = [](int a, int b) { return (a + b - 1) / b; };

  // zero barrier counters (ws is re-poisoned before every call)
  hipMemsetAsync(bars, 0, 512 * sizeof(unsigned), stream);

  // 1) char CNN + elmo concat (ctx rows 0..4095, qry rows 4096..4223)
  cnn_embed_kernel<<<4224, 128, 0, stream>>>(chars_ctx, chars_qry, elmo_ctx, elmo_qry,
                                             char_emb, conv_w, conv_b, x_all);

  // 2) highway x2
  for (int l = 0; l < 2; ++l) {
    gemm_abt<<<dim3(cdiv(356, BNT), cdiv(4224, BMT)), 256, 0, stream>>>(
        x_all, hw_gate_w + (size_t)l * 356 * 356, hw_gate_b + l * 356, gbuf, 4224, 356, 356);
    gemm_abt<<<dim3(cdiv(356, BNT), cdiv(4224, BMT)), 256, 0, stream>>>(
        x_all, hw_plain_w + (size_t)l * 356 * 356, hw_plain_b + l * 356, pbuf, 4224, 356, 356);
    highway_combine<<<cdiv(4224 * 356, 256), 256, 0, stream>>>(x_all, gbuf, pbuf, 4224 * 356);
  }

  // 3) ctx BiLSTM: xW precompute (both dirs in one GEMM: N=2848), then scans
  gemm_abt<<<dim3(cdiv(2848, BNT), cdiv(4224, BMT)), 256, 0, stream>>>(
      x_all, ctx_Wih, ctx_b, xw_all, 4224, 2848, 356);
  lstm_scan_kernel<<<64, 512, 0, stream>>>(xw_all, ctx_Whh, h0_ctx_c, CQ, 0, 4096, bars + 0);
  lstm_scan_kernel<<<64, 512, 0, stream>>>(xw_all, ctx_Whh, h0_ctx_q, CQ, 4096, 128, bars + 64);

  // 4) attention
  qdot_kernel<<<128, 64, 0, stream>>>(CQ + 4096ull * 712, sim_w, s2v);
  attn_row_kernel<<<4096, 256, 0, stream>>>(CQ, sim_w, s2v, rowm, qac);
  softmax_4096<<<1, 256, 0, stream>>>(rowm, rowa);
  q2c_kernel<<<cdiv(712, 256), 256, 0, stream>>>(CQ, rowa, q2cv);
  qac_finish_kernel<<<4096, 256, 0, stream>>>(CQ, q2cv, qac);

  // 5) mod1 BiLSTM (input 2848)
  gemm_abt<<<dim3(cdiv(2848, BNT), cdiv(4096, BMT)), 256, 0, stream>>>(
      qac, mod1_Wih, mod1_b, xw_all, 4096, 2848, 2848);
  lstm_scan_kernel<<<64, 512, 0, stream>>>(xw_all, mod1_Whh, h0_mod, M1, 0, 4096, bars + 128);

  // 6) mod2 BiLSTM (input 712)
  gemm_abt<<<dim3(cdiv(2848, BNT), cdiv(4096, BMT)), 256, 0, stream>>>(
      M1, mod2_Wih, mod2_b, xw_all, 4096, 2848, 712);
  lstm_scan_kernel<<<64, 512, 0, stream>>>(xw_all, mod2_Whh, h0_mod + 712, Mm, 0, 4096, bars + 192);

  // 7) pos1 = softmax([qac, M] @ pos1_w)
  logits_kernel<<<4096, 256, 0, stream>>>(qac, Mm, pos1_w, logits);
  softmax_4096<<<1, 256, 0, stream>>>(logits, outp);

  // 8) pos BiLSTM (input 712) then pos2
  gemm_abt<<<dim3(cdiv(2848, BNT), cdiv(4096, BMT)), 256, 0, stream>>>(
      Mm, pos_Wih, pos_b, xw_all, 4096, 2848, 712);
  lstm_scan_kernel<<<64, 512, 0, stream>>>(xw_all, pos_Whh, h0_pos, M2, 0, 4096, bars + 256);
  logits_kernel<<<4096, 256, 0, stream>>>(qac, M2, pos2_w, logits + 4096);
  softmax_4096<<<1, 256, 0, stream>>>(logits + 4096, outp + 4096);

  (void)in_sizes; (void)n_in; (void)out_size; (void)ws_size;
}

// Round 2
// 72097.540 us; speedup vs baseline: 1.0431x; 1.0431x over previous
//
#include <hip/hip_runtime.h>
#include <math.h>

// ---------------------------------------------------------------------------
// helpers
// ---------------------------------------------------------------------------
__device__ __forceinline__ float sigm(float x) { return 1.0f / (1.0f + __expf(-x)); }

__device__ __forceinline__ float waveSum(float v) {
#pragma unroll
  for (int off = 32; off > 0; off >>= 1) v += __shfl_xor(v, off);
  return v;
}

// ---------------------------------------------------------------------------
// char CNN + elmo concat  -> x_all (4224 x 356)
// ---------------------------------------------------------------------------
__global__ __launch_bounds__(128) void cnn_embed_kernel(
    const int* __restrict__ chars_ctx, const int* __restrict__ chars_qry,
    const float* __restrict__ elmo_ctx, const float* __restrict__ elmo_qry,
    const float* __restrict__ char_emb, const float* __restrict__ conv_w,
    const float* __restrict__ conv_b, float* __restrict__ x_all)
{
  int n = blockIdx.x;
  const int*   chars = (n < 4096) ? (chars_ctx + n * 16) : (chars_qry + (n - 4096) * 16);
  const float* elmo  = (n < 4096) ? (elmo_ctx + (size_t)n * 256)
                                  : (elmo_qry + (size_t)(n - 4096) * 256);
  __shared__ float xl[1600];   // [emb_dim=100][pos=16]
  __shared__ int   cidx[16];
  int tid = threadIdx.x;
  if (tid < 16) cidx[tid] = chars[tid];
  __syncthreads();
  for (int e = tid; e < 1600; e += 128) {
    int i = e >> 4, p = e & 15;
    xl[e] = char_emb[cidx[p] * 100 + i];
  }
  __syncthreads();
  if (tid < 100) {
    int o = tid;
    float acc[16];
#pragma unroll
    for (int p = 0; p < 16; ++p) acc[p] = 0.f;
    const float* wo = conv_w + o * 500;
    for (int i = 0; i < 100; ++i) {
      const float* xi = xl + i * 16;
#pragma unroll
      for (int k = 0; k < 5; ++k) {
        float w = wo[i * 5 + k];
#pragma unroll
        for (int p = 0; p < 16; ++p) {
          int src = p + k - 2;
          if (src >= 0 && src < 16) acc[p] += w * xi[src];
        }
      }
    }
    float m = acc[0];
#pragma unroll
    for (int p = 1; p < 16; ++p) m = fmaxf(m, acc[p]);
    x_all[(size_t)n * 356 + o] = m + conv_b[o];
  }
  for (int j = tid; j < 256; j += 128)
    x_all[(size_t)n * 356 + 100 + j] = elmo[j];
}

// ---------------------------------------------------------------------------
// generic fp32 GEMM:  C[M,N] = A[M,K] @ B[N,K]^T + bias[N]
// ---------------------------------------------------------------------------
#define BMT 64
#define BNT 64
#define BKT 16

__global__ __launch_bounds__(256) void gemm_abt(
    const float* __restrict__ A, const float* __restrict__ B,
    const float* __restrict__ bias, float* __restrict__ C,
    int M, int N, int K)
{
  __shared__ float As[BKT][BMT + 4];
  __shared__ float Bs[BKT][BNT + 4];
  int tid = threadIdx.x;
  int bm = blockIdx.y * BMT, bn = blockIdx.x * BNT;
  int tm = (tid >> 4) << 2;
  int tn = (tid & 15) << 2;
  float acc[4][4];
#pragma unroll
  for (int i = 0; i < 4; ++i)
#pragma unroll
    for (int j = 0; j < 4; ++j) acc[i][j] = 0.f;

  for (int k0 = 0; k0 < K; k0 += BKT) {
    for (int e = tid; e < BMT * BKT; e += 256) {
      int m = e >> 4, kk = e & 15;
      int gm = bm + m, gk = k0 + kk;
      As[kk][m] = (gm < M && gk < K) ? A[(size_t)gm * K + gk] : 0.f;
    }
    for (int e = tid; e < BNT * BKT; e += 256) {
      int nn = e >> 4, kk = e & 15;
      int gn = bn + nn, gk = k0 + kk;
      Bs[kk][nn] = (gn < N && gk < K) ? B[(size_t)gn * K + gk] : 0.f;
    }
    __syncthreads();
#pragma unroll
    for (int kk = 0; kk < BKT; ++kk) {
      float a[4], b[4];
#pragma unroll
      for (int i = 0; i < 4; ++i) a[i] = As[kk][tm + i];
#pragma unroll
      for (int j = 0; j < 4; ++j) b[j] = Bs[kk][tn + j];
#pragma unroll
      for (int i = 0; i < 4; ++i)
#pragma unroll
        for (int j = 0; j < 4; ++j) acc[i][j] += a[i] * b[j];
    }
    __syncthreads();
  }
#pragma unroll
  for (int i = 0; i < 4; ++i) {
    int gm = bm + tm + i;
    if (gm >= M) continue;
#pragma unroll
    for (int j = 0; j < 4; ++j) {
      int gn = bn + tn + j;
      if (gn < N) {
        float v = acc[i][j];
        if (bias) v += bias[gn];
        C[(size_t)gm * N + gn] = v;
      }
    }
  }
}

// ---------------------------------------------------------------------------
// highway combine
// ---------------------------------------------------------------------------
__global__ void highway_combine(float* __restrict__ x, const float* __restrict__ g,
                                const float* __restrict__ p, int total)
{
  int i = blockIdx.x * blockDim.x + threadIdx.x;
  if (i < total) {
    float gg = sigm(g[i]);
    float pp = fmaxf(p[i], 0.f);
    x[i] = gg * pp + (1.f - gg) * x[i];
  }
}

// ---------------------------------------------------------------------------
// persistent BiLSTM scan kernel, v2: epoch-packed u64 exchange.
// grid = 32 blocks (dir = blockIdx.x&1, wg = blockIdx.x>>1, 16 WGs/dir),
// block = 512 (8 waves). Each WG owns SLICE=23 hidden units (92 Whh rows)
// in VGPRs (12 rows/wave x 6 col-chunks of 64). Each step, every hidden unit
// is published as ONE 64-bit word { epoch:32 | float_bits:32 } at agent
// scope (relaxed — atomicity of the 8B word carries the ordering), into a
// parity-double-buffered exchange array. Consumers spin on their own word
// with relaxed loads: no RMW contention, no cache invalidations, one LLC
// round trip per step.  xw for step t+1 is prefetched during step t.
// ---------------------------------------------------------------------------
#define NWG 16
#define SLICE 23   // 16*23 = 368 >= 356

__global__ __launch_bounds__(512, 1) void lstm_scan_kernel(
    const float* __restrict__ xw, const float* __restrict__ whh,
    const float* __restrict__ h0, float* __restrict__ out,
    int row0, int N, unsigned long long* exbuf)
{
  const int tid  = threadIdx.x;
  const int dir  = blockIdx.x & 1;
  const int wg   = blockIdx.x >> 1;
  const int lane = tid & 63;
  const int wv   = tid >> 6;          // 0..7
  const int j0   = wg * SLICE;
  const float* whh_d = whh + (size_t)dir * 1424 * 356;
  const float* h0_d  = h0 + dir * 356;
  const int xcol0 = dir * 1424;
  const int ocol0 = dir * 356;
  unsigned long long* exd = exbuf + dir * 712;   // [parity][356]

  __shared__ float h_lds[384];
  __shared__ float z_lds[4 * SLICE];   // [gate][jj]

  // --- z-duty mapping: tid < 92 handles one (gate,jj) element of z/xw
  const bool zduty = (tid < 4 * SLICE);
  int zgate = 0, zjj = 0, zj = 0;
  bool zvalid = false;
  size_t xcol = 0;
  if (zduty) {
    zgate = tid / SLICE; zjj = tid % SLICE; zj = j0 + zjj;
    zvalid = (zj < 356);
    xcol = (size_t)(xcol0 + zgate * 356 + zj);
  }

  // --- Whh slice -> registers: wave wv, q=0..11 -> rr = wv*12+q
  float wreg[12][6];
#pragma unroll
  for (int q = 0; q < 12; ++q) {
    int rr = wv * 12 + q;
    bool rv = (rr < 4 * SLICE);
    int gate = rv ? (rr / SLICE) : 0, jj = rv ? (rr % SLICE) : 0;
    int j = j0 + jj;
    bool v = rv && (j < 356);
    int row_g = gate * 356 + j;
#pragma unroll
    for (int ii = 0; ii < 6; ++ii) {
      int k = lane + ii * 64;
      wreg[q][ii] = (v && k < 356) ? whh_d[(size_t)row_g * 356 + k] : 0.f;
    }
  }

  // init h (pad zeroed), per-thread c for owned unit
  for (int k = tid; k < 384; k += 512) h_lds[k] = (k < 356) ? h0_d[k] : 0.f;
  float c_reg = 0.f;
  if (tid < SLICE) { int j = j0 + tid; if (j < 356) c_reg = h0_d[j]; }

  // preload xw for t=0
  float xw_cur = 0.f;
  {
    int row = dir ? (N - 1) : 0;
    if (zvalid) xw_cur = xw[(size_t)(row0 + row) * 2848 + xcol];
  }
  __syncthreads();

  for (int t = 0; t < N; ++t) {
    int row = dir ? (N - 1 - t) : t;
    size_t grow = (size_t)(row0 + row);

    // stage A: z init from prefetched xw; issue prefetch for t+1
    if (zduty) z_lds[tid] = zvalid ? xw_cur : 0.f;
    float xw_nx = 0.f;
    {
      int tn = (t + 1 < N) ? (t + 1) : (N - 1);
      int rown = dir ? (N - 1 - tn) : tn;
      if (zvalid) xw_nx = xw[(size_t)(row0 + rown) * 2848 + xcol];
    }
    __syncthreads();

    // stage B: dots  z[rr] += wreg_row . h
#pragma unroll
    for (int q = 0; q < 12; ++q) {
      float s = 0.f;
#pragma unroll
      for (int ii = 0; ii < 6; ++ii) s += wreg[q][ii] * h_lds[lane + ii * 64];
      s = waveSum(s);
      int rr = wv * 12 + q;
      if (lane == 0 && rr < 4 * SLICE) z_lds[rr] += s;
    }
    __syncthreads();

    // stage C: gate update + publish packed (epoch|h)
    if (tid < SLICE) {
      int j = j0 + tid;
      if (j < 356) {
        float zi = z_lds[tid], zf = z_lds[SLICE + tid];
        float zg = z_lds[2 * SLICE + tid], zo = z_lds[3 * SLICE + tid];
        float c = sigm(zf) * c_reg + sigm(zi) * tanhf(zg);
        float h = sigm(zo) * tanhf(c);
        c_reg = c;
        out[grow * 712 + ocol0 + j] = h;
        unsigned long long pk =
            ((unsigned long long)(unsigned)(t + 1) << 32) |
            (unsigned long long)__float_as_uint(h);
        __hip_atomic_store(&exd[(size_t)(t & 1) * 356 + j], pk,
                           __ATOMIC_RELAXED, __HIP_MEMORY_SCOPE_AGENT);
      }
    }

    // stage D: poll own word until fresh, deposit into h_lds
    if (tid < 356) {
      unsigned long long* p = &exd[(size_t)(t & 1) * 356 + tid];
      unsigned ep = (unsigned)(t + 1);
      unsigned long long v;
      do {
        v = __hip_atomic_load(p, __ATOMIC_RELAXED, __HIP_MEMORY_SCOPE_AGENT);
      } while ((unsigned)(v >> 32) != ep);
      h_lds[tid] = __uint_as_float((unsigned)v);
    }
    __syncthreads();

    xw_cur = xw_nx;
  }
}

// ---------------------------------------------------------------------------
// attention: s2[j] = Q[j] . w_q
// ---------------------------------------------------------------------------
__global__ __launch_bounds__(64) void qdot_kernel(
    const float* __restrict__ Q, const float* __restrict__ sim_w, float* __restrict__ s2)
{
  int j = blockIdx.x;
  int lane = threadIdx.x;
  const float* q  = Q + (size_t)j * 712;
  const float* wq = sim_w + 712;
  float s = 0.f;
  for (int k = lane; k < 712; k += 64) s += q[k] * wq[k];
  s = waveSum(s);
  if (lane == 0) s2[j] = s;
}

// ---------------------------------------------------------------------------
// per-context-row attention + qac[0,2136)
// ---------------------------------------------------------------------------
__global__ __launch_bounds__(256) void attn_row_kernel(
    const float* __restrict__ CQ, const float* __restrict__ sim_w,
    const float* __restrict__ s2, float* __restrict__ rowm, float* __restrict__ qac)
{
  int i = blockIdx.x;   // 0..4095
  int tid = threadIdx.x;
  const float* Q = CQ + (size_t)4096 * 712;
  __shared__ float crow[712], cw[712], prow[128], red[256];
  const float* ci = CQ + (size_t)i * 712;

  float s1p = 0.f;
  for (int k = tid; k < 712; k += 256) {
    float v = ci[k];
    crow[k] = v;
    cw[k] = v * sim_w[1424 + k];
    s1p += v * sim_w[k];
  }
  red[tid] = s1p;
  __syncthreads();
  for (int s = 128; s > 0; s >>= 1) { if (tid < s) red[tid] += red[tid + s]; __syncthreads(); }
  float s1 = red[0];

  int lane = tid & 63, wv = tid >> 6;
  for (int j = wv; j < 128; j += 4) {
    const float* qj = Q + (size_t)j * 712;
    float s = 0.f;
    for (int k = lane; k < 712; k += 64) s += cw[k] * qj[k];
    s = waveSum(s);
    if (lane == 0) prow[j] = s1 + s2[j] + s;
  }
  __syncthreads();

  float v = (tid < 128) ? prow[tid] : -1e30f;
  red[tid] = v;
  __syncthreads();
  for (int s = 128; s > 0; s >>= 1) { if (tid < s) red[tid] = fmaxf(red[tid], red[tid + s]); __syncthreads(); }
  float m = red[0];
  __syncthreads();
  float e = (tid < 128) ? __expf(prow[tid] - m) : 0.f;
  red[tid] = e;
  __syncthreads();
  for (int s = 128; s > 0; s >>= 1) { if (tid < s) red[tid] += red[tid + s]; __syncthreads(); }
  float denom = red[0];
  if (tid < 128) prow[tid] = e / denom;
  if (tid == 0) rowm[i] = m;
  __syncthreads();

  size_t qb = (size_t)i * 2848;
  for (int k = tid; k < 712; k += 256) {
    float acc = 0.f;
    for (int j = 0; j < 128; ++j) acc += prow[j] * Q[(size_t)j * 712 + k];
    float cv = crow[k];
    qac[qb + k]        = cv;
    qac[qb + 712 + k]  = acc;
    qac[qb + 1424 + k] = cv * acc;
  }
}

// ---------------------------------------------------------------------------
// softmax over a length-4096 vector (single block)
// ---------------------------------------------------------------------------
__global__ __launch_bounds__(256) void softmax_4096(const float* __restrict__ in,
                                                    float* __restrict__ out)
{
  __shared__ float red[256];
  int tid = threadIdx.x;
  float m = -1e30f;
  for (int i = tid; i < 4096; i += 256) m = fmaxf(m, in[i]);
  red[tid] = m;
  __syncthreads();
  for (int s = 128; s > 0; s >>= 1) { if (tid < s) red[tid] = fmaxf(red[tid], red[tid + s]); __syncthreads(); }
  m = red[0];
  __syncthreads();
  float sum = 0.f;
  for (int i = tid; i < 4096; i += 256) sum += __expf(in[i] - m);
  red[tid] = sum;
  __syncthreads();
  for (int s = 128; s > 0; s >>= 1) { if (tid < s) red[tid] += red[tid + s]; __syncthreads(); }
  float denom = red[0];
  for (int i = tid; i < 4096; i += 256) out[i] = __expf(in[i] - m) / denom;
}

// ---------------------------------------------------------------------------
// q2c[k] = sum_i a[i]*C[i,k]
// ---------------------------------------------------------------------------
__global__ __launch_bounds__(256) void q2c_kernel(
    const float* __restrict__ CQ, const float* __restrict__ rowa, float* __restrict__ q2c)
{
  int k = blockIdx.x * 256 + threadIdx.x;
  if (k < 712) {
    float acc = 0.f;
    for (int i = 0; i < 4096; ++i) acc += rowa[i] * CQ[(size_t)i * 712 + k];
    q2c[k] = acc;
  }
}

__global__ __launch_bounds__(256) void qac_finish_kernel(
    const float* __restrict__ CQ, const float* __restrict__ q2c, float* __restrict__ qac)
{
  int i = blockIdx.x;
  int tid = threadIdx.x;
  for (int k = tid; k < 712; k += 256)
    qac[(size_t)i * 2848 + 2136 + k] = CQ[(size_t)i * 712 + k] * q2c[k];
}

__global__ __launch_bounds__(256) void logits_kernel(
    const float* __restrict__ qac, const float* __restrict__ Mx,
    const float* __restrict__ w, float* __restrict__ logits)
{
  int i = blockIdx.x, tid = threadIdx.x;
  __shared__ float red[256];
  float s = 0.f;
  const float* qr = qac + (size_t)i * 2848;
  for (int k = tid; k < 2848; k += 256) s += qr[k] * w[k];
  const float* mr = Mx + (size_t)i * 712;
  for (int k = tid; k < 712; k += 256) s += mr[k] * w[2848 + k];
  red[tid] = s;
  __syncthreads();
  for (int st = 128; st > 0; st >>= 1) { if (tid < st) red[tid] += red[tid + st]; __syncthreads(); }
  if (tid == 0) logits[i] = red[0];
}

// ---------------------------------------------------------------------------
// host side
// ---------------------------------------------------------------------------
extern "C" void kernel_launch(void* const* d_in, const int* in_sizes, int n_in,
                              void* d_out, int out_size, void* d_ws, size_t ws_size,
                              hipStream_t stream)
{
  const int*   chars_ctx = (const int*)d_in[0];
  const int*   chars_qry = (const int*)d_in[1];
  const float* elmo_ctx  = (const float*)d_in[2];
  const float* elmo_qry  = (const float*)d_in[3];
  const float* char_emb  = (const float*)d_in[4];
  const float* conv_w    = (const float*)d_in[5];
  const float* conv_b    = (const float*)d_in[6];
  const float* hw_plain_w = (const float*)d_in[7];
  const float* hw_plain_b = (const float*)d_in[8];
  const float* hw_gate_w  = (const float*)d_in[9];
  const float* hw_gate_b  = (const float*)d_in[10];
  const float* ctx_Wih   = (const float*)d_in[11];
  const float* ctx_Whh   = (const float*)d_in[12];
  const float* ctx_b     = (const float*)d_in[13];
  const float* sim_w     = (const float*)d_in[14];
  const float* mod1_Wih  = (const float*)d_in[15];
  const float* mod1_Whh  = (const float*)d_in[16];
  const float* mod1_b    = (const float*)d_in[17];
  const float* mod2_Wih  = (const float*)d_in[18];
  const float* mod2_Whh  = (const float*)d_in[19];
  const float* mod2_b    = (const float*)d_in[20];
  const float* pos_Wih   = (const float*)d_in[21];
  const float* pos_Whh   = (const float*)d_in[22];
  const float* pos_b     = (const float*)d_in[23];
  const float* pos1_w    = (const float*)d_in[24];
  const float* pos2_w    = (const float*)d_in[25];
  const float* h0_ctx_c  = (const float*)d_in[26];
  const float* h0_ctx_q  = (const float*)d_in[27];
  const float* h0_mod    = (const float*)d_in[28];
  const float* h0_pos    = (const float*)d_in[29];
  float* outp = (float*)d_out;

  float* ws = (float*)d_ws;
  size_t off = 0;
  auto alloc = [&](size_t n) { float* p = ws + off; off += n; return p; };
  float* x_all  = alloc(4224ull * 356);
  float* gbuf   = alloc(4224ull * 356);
  float* pbuf   = alloc(4224ull * 356);
  float* xw_all = alloc(4224ull * 2848);
  float* CQ     = alloc(4224ull * 712);
  float* M1     = alloc(4096ull * 712);
  float* Mm     = alloc(4096ull * 712);
  float* M2     = alloc(4096ull * 712);
  float* qac    = alloc(4096ull * 2848);
  float* s2v    = alloc(128);
  float* rowm   = alloc(4096);
  float* rowa   = alloc(4096);
  float* q2cv   = alloc(1024);
  float* logits = alloc(8192);
  off = (off + 1) & ~(size_t)1;                    // 8B align
  unsigned long long* exbuf = (unsigned long long*)(ws + off);
  // 5 scans x [2 dirs][2 parity][356] u64 — poisoned 0xAA by the harness;
  // 0xAAAAAAAA never equals any epoch t+1 <= 4096, so no memset needed.
  off += 5ull * 1424 * 2;

  auto cdiv = [](int a, int b) { return (a + b - 1) / b; };

  // 1) char CNN + elmo concat
  cnn_embed_kernel<<<4224, 128, 0, stream>>>(chars_ctx, chars_qry, elmo_ctx, elmo_qry,
                                             char_emb, conv_w, conv_b, x_all);

  // 2) highway x2
  for (int l = 0; l < 2; ++l) {
    gemm_abt<<<dim3(cdiv(356, BNT), cdiv(4224, BMT)), 256, 0, stream>>>(
        x_all, hw_gate_w + (size_t)l * 356 * 356, hw_gate_b + l * 356, gbuf, 4224, 356, 356);
    gemm_abt<<<dim3(cdiv(356, BNT), cdiv(4224, BMT)), 256, 0, stream>>>(
        x_all, hw_plain_w + (size_t)l * 356 * 356, hw_plain_b + l * 356, pbuf, 4224, 356, 356);
    highway_combine<<<cdiv(4224 * 356, 256), 256, 0, stream>>>(x_all, gbuf, pbuf, 4224 * 356);
  }

  // 3) ctx BiLSTM
  gemm_abt<<<dim3(cdiv(2848, BNT), cdiv(4224, BMT)), 256, 0, stream>>>(
      x_all, ctx_Wih, ctx_b, xw_all, 4224, 2848, 356);
  lstm_scan_kernel<<<2 * NWG, 512, 0, stream>>>(xw_all, ctx_Whh, h0_ctx_c, CQ, 0, 4096,
                                                exbuf + 0ull * 1424);
  lstm_scan_kernel<<<2 * NWG, 512, 0, stream>>>(xw_all, ctx_Whh, h0_ctx_q, CQ, 4096, 128,
                                                exbuf + 1ull * 1424);

  // 4) attention
  qdot_kernel<<<128, 64, 0, stream>>>(CQ + 4096ull * 712, sim_w, s2v);
  attn_row_kernel<<<4096, 256, 0, stream>>>(CQ, sim_w, s2v, rowm, qac);
  softmax_4096<<<1, 256, 0, stream>>>(rowm, rowa);
  q2c_kernel<<<cdiv(712, 256), 256, 0, stream>>>(CQ, rowa, q2cv);
  qac_finish_kernel<<<4096, 256, 0, stream>>>(CQ, q2cv, qac);

  // 5) mod1 BiLSTM (input 2848)
  gemm_abt<<<dim3(cdiv(2848, BNT), cdiv(4096, BMT)), 256, 0, stream>>>(
      qac, mod1_Wih, mod1_b, xw_all, 4096, 2848, 2848);
  lstm_scan_kernel<<<2 * NWG, 512, 0, stream>>>(xw_all, mod1_Whh, h0_mod, M1, 0, 4096,
                                                exbuf + 2ull * 1424);

  // 6) mod2 BiLSTM (input 712)
  gemm_abt<<<dim3(cdiv(2848, BNT), cdiv(4096, BMT)), 256, 0, stream>>>(
      M1, mod2_Wih, mod2_b, xw_all, 4096, 2848, 712);
  lstm_scan_kernel<<<2 * NWG, 512, 0, stream>>>(xw_all, mod2_Whh, h0_mod + 712, Mm, 0, 4096,
                                                exbuf + 3ull * 1424);

  // 7) pos1
  logits_kernel<<<4096, 256, 0, stream>>>(qac, Mm, pos1_w, logits);
  softmax_4096<<<1, 256, 0, stream>>>(logits, outp);

  // 8) pos BiLSTM then pos2
  gemm_abt<<<dim3(cdiv(2848, BNT), cdiv(4096, BMT)), 256, 0, stream>>>(
      Mm, pos_Wih, pos_b, xw_all, 4096, 2848, 712);
  lstm_scan_kernel<<<2 * NWG, 512, 0, stream>>>(xw_all, pos_Whh, h0_pos, M2, 0, 4096,
                                                exbuf + 4ull * 1424);
  logits_kernel<<<4096, 256, 0, stream>>>(qac, M2, pos2_w, logits + 4096);
  softmax_4096<<<1, 256, 0, stream>>>(logits + 4096, outp + 4096);

  (void)in_sizes; (void)n_in; (void)out_size; (void)ws_size;
}